// Round 12
// baseline (694.810 us; speedup 1.0000x reference)
//
#include <hip/hip_runtime.h>
#include <stdint.h>

// Problem constants
#define B_SZ   32
#define NIN    2312
#define NHID   512
#define NOUT   10
#define T_SZ   350
#define NW32   73                 // ceil(2312/32) bitmask words per input column
#define NW64   8                  // 512/64 ballot words per hidden column
#define NHALF  256                // output half-width for L2-resident W1
#define NROW   2313               // NIN + 1 dummy zero row (branch-free padding)

// psp (SRM) kernel eps[n] = CS * n * DS^n, DS = exp(-0.1), CS = e/10
#define DS_D   0.9048374180359595
#define CS_D   0.2718281828459045
#define D100_D 4.5399929762484854e-05   // exp(-10) = DS^100
// refractory recurrence in fp32, exactly like the reference scan
#define DREF_F 0.36787944117144233f     // exp(-1)
#define CREF_F -54.36563656918091f      // -2*10*e

// scan chunking (k45/k6): 7 chunks of 50; psp-IIR warm-started <=100 steps
// early is EXACT (FIR truncated at 100 taps); refractory burn-in error decays
// e^-n -> < 1e-28 by chunk start (absorbed below fp32 ulp).
#define NCHUNK 7
#define CLEN   50
#define NPF    10                 // ring depth; 50/100/150 all %10==0

// k3 column-batched gather
#define GCOL   32                 // columns per block
#define NGRP   350                // 11200 / 32

// ---------------------------------------------------------------------------
// K12: fused bitpack (blocks 0..2335) + W1 half-split pack (2336..3503) +
//      dummy-zero-row fill (block 3504). Bitpack float4 streaming.
__global__ __launch_bounds__(384) void k12(const float* __restrict__ x,
                                           const float* __restrict__ W1,
                                           uint32_t* __restrict__ bits1,
                                           float* __restrict__ W1s) {
    __shared__ float lds[32 * T_SZ];   // 44.8 KB
    const int bid = blockIdx.x;
    const int tid = threadIdx.x;
    if (bid < NW32 * B_SZ) {
        // --- bitpack: block = (b, w); contiguous rowsx350 tile -> LDS -> pack
        const int w = bid % NW32;
        const int b = bid / NW32;
        const int rows = (NIN - (w << 5) < 32) ? (NIN - (w << 5)) : 32;  // 32 or 8
        const float* base = x + ((size_t)(b * NIN + (w << 5))) * T_SZ;
        const int nf4 = (rows * T_SZ) >> 2;     // rows even -> divisible by 4
        for (int f = tid; f < nf4; f += 384)
            ((float4*)lds)[f] = ((const float4*)base)[f];
        __syncthreads();
        if (tid < T_SZ) {
            uint32_t bits = 0;
            for (int j = 0; j < rows; ++j)
                bits |= (lds[j * T_SZ + tid] > 0.5f) ? (1u << j) : 0u;
            bits1[(size_t)(b * T_SZ + tid) * NW32 + w] = bits;
        }
    } else if (bid < NW32 * B_SZ + NW32 * 16) {
        // --- pack W1 [512, 2312] -> W1s[h][i][256], h = o>>8
        float (*tile)[33] = (float (*)[33])lds;
        const int bb = bid - NW32 * B_SZ;
        const int i0 = (bb % NW32) * 32, o0 = (bb / NW32) * 32;
        const int tx = tid & 31, ty = tid >> 5;  // ty 0..11
#pragma unroll
        for (int r = 0; r < 3; ++r) {
            int row = ty + 12 * r;
            if (row < 32) {
                int o = o0 + row, i = i0 + tx;
                if (i < NIN) tile[row][tx] = W1[(size_t)o * NIN + i];
            }
        }
        __syncthreads();
#pragma unroll
        for (int r = 0; r < 3; ++r) {
            int row = ty + 12 * r;
            if (row < 32) {
                int i = i0 + row, o = o0 + tx;
                if (i < NIN)
                    W1s[((size_t)(o >> 8) * NROW + i) * NHALF + (o & 255)] = tile[tx][row];
            }
        }
    } else {
        // --- dummy zero row i = NIN for both halves
        if (tid < NHALF) {
            W1s[((size_t)0 * NROW + NIN) * NHALF + tid] = 0.0f;
            W1s[((size_t)1 * NROW + NIN) * NHALF + tid] = 0.0f;
        }
    }
}

// ---------------------------------------------------------------------------
// K3: column-batched sparse dense1. Block = (column-group of 32, half).
// A row active in >=1 of the 32 columns is fetched ONCE from L2 and serves
// all its active columns: traffic 2.66 GB -> ~1.3 GB (x2.05 reduction).
// Per-row 32-bit column masks built by an LDS bitmask transpose; accumulators
// float2 acc[32] indexed ONLY by compile-time constants (no spill, R7 lesson);
// mask walk via hierarchical wave-uniform scalar branches (readfirstlane).
__global__ __launch_bounds__(256) void k3_dense1(const uint32_t* __restrict__ bits1,
                                                 const float* __restrict__ W1s,
                                                 float* __restrict__ z1ct) {
    __shared__ uint32_t colw[GCOL * NW32];      // [c*73+w], 9.3 KB
    __shared__ uint32_t orw[128];               // OR over cols, zero-padded
    __shared__ uint32_t rowmask[GCOL * NW32];   // [w*32+j] -> 32-bit col mask
    __shared__ uint16_t pfx[80];
    __shared__ uint16_t idxbuf[NIN + 8];
    __shared__ float red[GCOL][NHALF];          // 32 KB (partials, then finals)

    const int bt0 = blockIdx.x * GCOL;          // 32 consecutive (b,t) columns
    const int h = blockIdx.y;                   // 0 or 1
    const int tid = threadIdx.x;
    const int lane = tid & 63;
    const int wv = tid >> 6;
    const int g = tid >> 7;                     // row-parity group 0/1
    const int l = tid & 127;                    // owns outputs 2l, 2l+1

    // 1. load the 32 columns' mask words (contiguous in bits1)
    const uint32_t* bsrc = bits1 + (size_t)bt0 * NW32;
    if (tid < 128) orw[tid] = 0;
    for (int k = tid; k < GCOL * NW32; k += 256) colw[k] = bsrc[k];
    __syncthreads();

    // 2. OR-words (touched-row detector)
    if (tid < NW32) {
        uint32_t o = 0;
#pragma unroll
        for (int c = 0; c < GCOL; ++c) o |= colw[c * NW32 + tid];
        orw[tid] = o;
    }
    // 3. 32x32 bit transpose -> per-row column masks
    for (int k = tid; k < GCOL * NW32; k += 256) {   // k = w*32 + j = row id
        const int w = k >> 5, j = k & 31;
        uint32_t m = 0;
#pragma unroll
        for (int c = 0; c < GCOL; ++c)
            m |= ((colw[c * NW32 + w] >> j) & 1u) << c;
        rowmask[k] = m;
    }
    __syncthreads();

    // 4. prefix scan of popcounts over OR-words (wave 0), then compaction
    if (wv == 0) {
        uint32_t w0 = orw[lane];
        uint32_t w1 = orw[lane + 64];
        int p0 = __popc(w0), p1 = __popc(w1);
        int s0 = p0, s1 = p1;
#pragma unroll
        for (int off = 1; off < 64; off <<= 1) {
            int u0 = __shfl_up(s0, off);
            int u1 = __shfl_up(s1, off);
            if (lane >= off) { s0 += u0; s1 += u1; }
        }
        int tot0 = __shfl(s0, 63);
        pfx[lane] = (uint16_t)(s0 - p0);
        if (lane < 9) pfx[lane + 64] = (uint16_t)(tot0 + s1 - p1);
        if (lane == 8) pfx[73] = (uint16_t)(tot0 + s1);   // ntot
    }
    __syncthreads();
    const int ntot = pfx[73];
    const int npad = (ntot + 7) & ~7;
    if (tid < NW32) {
        uint32_t m = orw[tid];
        int p = pfx[tid];
        while (m) {
            int j = __builtin_ctz(m);
            m &= m - 1;
            idxbuf[p++] = (uint16_t)((tid << 5) + j);
        }
    }
    if (tid >= 248) {                   // pad to x8 with dummy zero row
        int k = tid - 248;
        if (ntot + k < npad) idxbuf[ntot + k] = (uint16_t)NIN;
        // rowmask[NIN] is 0 (bit 8 of word 72 never set by bitpack)
    }
    __syncthreads();

    // 5. main loop: groups take alternating touched rows, 4 rows in flight
    const float* Wh = W1s + (size_t)h * NROW * NHALF;
    float2 acc[GCOL];
#pragma unroll
    for (int c = 0; c < GCOL; ++c) acc[c] = make_float2(0.f, 0.f);

#define PROCROW(MM, VV)                                                     \
    {                                                                       \
        uint32_t mu = __builtin_amdgcn_readfirstlane((int)(MM));            \
        _Pragma("unroll")                                                   \
        for (int q = 0; q < 4; ++q) {                                       \
            if (mu & (0xFFu << (q * 8))) {                                  \
                _Pragma("unroll")                                           \
                for (int c8 = 0; c8 < 8; ++c8) {                            \
                    const int c = q * 8 + c8;                               \
                    if (mu & (1u << c)) {                                   \
                        acc[c].x += (VV).x;                                 \
                        acc[c].y += (VV).y;                                 \
                    }                                                       \
                }                                                           \
            }                                                               \
        }                                                                   \
    }

    for (int r = g; r < npad; r += 8) {
        const int i0 = idxbuf[r],     i1 = idxbuf[r + 2];
        const int i2 = idxbuf[r + 4], i3 = idxbuf[r + 6];
        const uint32_t m0 = rowmask[i0], m1 = rowmask[i1];
        const uint32_t m2 = rowmask[i2], m3 = rowmask[i3];
        const float2 v0 = *(const float2*)(Wh + (size_t)i0 * NHALF + 2 * l);
        const float2 v1 = *(const float2*)(Wh + (size_t)i1 * NHALF + 2 * l);
        const float2 v2 = *(const float2*)(Wh + (size_t)i2 * NHALF + 2 * l);
        const float2 v3 = *(const float2*)(Wh + (size_t)i3 * NHALF + 2 * l);
        PROCROW(m0, v0)
        PROCROW(m1, v1)
        PROCROW(m2, v2)
        PROCROW(m3, v3)
    }
#undef PROCROW

    // 6. cross-group reduction in LDS, then store
    if (g == 1) {
#pragma unroll
        for (int c = 0; c < GCOL; ++c)
            *(float2*)&red[c][2 * l] = acc[c];
    }
    __syncthreads();
    if (g == 0) {
#pragma unroll
        for (int c = 0; c < GCOL; ++c) {
            float2 o = *(float2*)&red[c][2 * l];
            o.x += acc[c].x;
            o.y += acc[c].y;
            *(float2*)&red[c][2 * l] = o;
        }
    }
    __syncthreads();
    const int och = (h << 8) + tid;
    const int oc = och >> 6, l6 = och & 63;
#pragma unroll
    for (int c = 0; c < GCOL; ++c) {
        const int bt = bt0 + c;
        const int b = bt / T_SZ, t = bt - b * T_SZ;
        z1ct[((size_t)(b * NW64 + oc) * T_SZ + t) * 64 + l6] = red[c][tid];
    }
}

// ---------------------------------------------------------------------------
// K45: fused layer-1 scan + dense2. Block = (b, chunk), 512 threads = 8 waves;
// wave wv scans channels wv*64..+63 (chunked IIR, exact), ballots into LDS;
// then 500 (t,o) pairs compute z2 in the same wv/ctz-ascending order.
__global__ __launch_bounds__(512) void k45(const float* __restrict__ z1ct,
                                           const float* __restrict__ W2,
                                           float* __restrict__ z2ct) {
    __shared__ float W2s[NHID * NOUT];      // [c][o], 20 KB
    __shared__ uint64_t sw[CLEN][NW64];     // s1 ballot words for my 50 t's
    const int tid = threadIdx.x;
    const int wv = tid >> 6, lane = tid & 63;
    const int b = blockIdx.x / NCHUNK;
    const int ck = blockIdx.x % NCHUNK;
    const int tstart = ck * CLEN;
    const int tend = tstart + CLEN;
    const int t0 = (tstart >= 100) ? tstart - 100 : 0;

    for (int k = tid; k < NHID * NOUT; k += 512) {
        int c = k / NOUT, o = k - c * NOUT;
        W2s[k] = W2[(size_t)o * NHID + c];
    }

    // ---- layer-1 chunked scan (identical math to old k4)
    const float* base = z1ct + (size_t)(b * NW64 + wv) * T_SZ * 64 + lane;
    double A = 0.0, Bs = 0.0, A2 = 0.0, Bs2 = 0.0;
    float ra = 0.0f, rb = 0.0f;
    const double TAIL = D100_D * CS_D;
    float xb[NPF], xdb[NPF];
#pragma unroll
    for (int i = 0; i < NPF; ++i) {
        int t = t0 + i;
        xb[i] = base[(size_t)t * 64];
        int td = t - 100;
        xdb[i] = (td >= 0) ? base[(size_t)td * 64] : 0.0f;
    }
    for (int tb = t0; tb < tend; tb += NPF) {
#pragma unroll
        for (int i = 0; i < NPF; ++i) {
            const int t = tb + i;
            float x = xb[i], xd = xdb[i];
            const int tn = t + NPF;
            xb[i] = (tn < T_SZ) ? base[(size_t)tn * 64] : 0.0f;
            const int td = tn - 100;
            xdb[i] = (td >= 0) ? base[(size_t)td * 64] : 0.0f;
            Bs = DS_D * Bs + DS_D * A;
            A = DS_D * A + (double)x;
            Bs2 = DS_D * Bs2 + DS_D * A2;
            A2 = DS_D * A2 + (double)xd;
            double y = CS_D * Bs - TAIL * (Bs2 + 100.0 * A2);
            float u = (float)y + CREF_F * rb;
            float s = (u >= 10.0f) ? 1.0f : 0.0f;
            float ran = DREF_F * ra + s;
            float rbn = DREF_F * rb + DREF_F * ra;
            ra = ran; rb = rbn;
            uint64_t mball = __ballot(s != 0.0f);
            if (t >= tstart && lane == 0) sw[t - tstart][wv] = mball;
        }
    }
    __syncthreads();

    // ---- dense2 for my 50 t's (same order as old k5 -> bit-identical)
    if (tid < CLEN * NOUT) {                // 500 of 512
        const int tr = tid / NOUT;
        const int o = tid - tr * NOUT;
        const int t = tstart + tr;
        float acc = 0.f;
#pragma unroll
        for (int w2 = 0; w2 < NW64; ++w2) {
            uint64_t m = sw[tr][w2];
            while (m) {
                int j = __builtin_ctzll(m);
                m &= m - 1;
                acc += W2s[((w2 << 6) + j) * NOUT + o];
            }
        }
        const int bo = b * NOUT + o;
        z2ct[((size_t)(bo >> 6) * T_SZ + t) * 64 + (bo & 63)] = acc;
    }
}

// ---------------------------------------------------------------------------
// K6: fused psp-IIR + refractory scan, layer 2, chunked. Writes [B, NOUT, T].
__global__ __launch_bounds__(64) void k6_fir_scan2(const float* __restrict__ z2ct,
                                                   float* __restrict__ out) {
    const int lane = threadIdx.x;
    const int g = blockIdx.x / NCHUNK;    // bo group 0..4
    const int ck = blockIdx.x % NCHUNK;
    const int tstart = ck * CLEN;
    const int tend = tstart + CLEN;
    const int t0 = (tstart >= 100) ? tstart - 100 : 0;
    const int bo = (g << 6) + lane;       // 0..319
    const float* base = z2ct + (size_t)g * T_SZ * 64 + lane;
    float* op = out + (size_t)bo * T_SZ;
    double A = 0.0, Bs = 0.0, A2 = 0.0, Bs2 = 0.0;
    float ra = 0.0f, rb = 0.0f;
    const double TAIL = D100_D * CS_D;
    float xb[NPF], xdb[NPF];
#pragma unroll
    for (int i = 0; i < NPF; ++i) {
        int t = t0 + i;
        xb[i] = base[(size_t)t * 64];
        int td = t - 100;
        xdb[i] = (td >= 0) ? base[(size_t)td * 64] : 0.0f;
    }
    for (int tb = t0; tb < tend; tb += NPF) {
#pragma unroll
        for (int i = 0; i < NPF; ++i) {
            const int t = tb + i;
            float x = xb[i], xd = xdb[i];
            const int tn = t + NPF;
            xb[i] = (tn < T_SZ) ? base[(size_t)tn * 64] : 0.0f;
            const int td = tn - 100;
            xdb[i] = (td >= 0) ? base[(size_t)td * 64] : 0.0f;
            Bs = DS_D * Bs + DS_D * A;
            A = DS_D * A + (double)x;
            Bs2 = DS_D * Bs2 + DS_D * A2;
            A2 = DS_D * A2 + (double)xd;
            double y = CS_D * Bs - TAIL * (Bs2 + 100.0 * A2);
            float u = (float)y + CREF_F * rb;
            float s = (u >= 10.0f) ? 1.0f : 0.0f;
            float ran = DREF_F * ra + s;
            float rbn = DREF_F * rb + DREF_F * ra;
            ra = ran; rb = rbn;
            if (t >= tstart) op[t] = s;
        }
    }
}

// ---------------------------------------------------------------------------
extern "C" void kernel_launch(void* const* d_in, const int* in_sizes, int n_in,
                              void* d_out, int out_size, void* d_ws, size_t ws_size,
                              hipStream_t stream) {
    const float* spikeInput = (const float*)d_in[0];  // [32, 2312, 350]
    const float* W1 = (const float*)d_in[1];          // [512, 2312]
    const float* W2 = (const float*)d_in[2];          // [10, 512]
    float* out = (float*)d_out;                       // [32, 10, 350]

    char* ws = (char*)d_ws;
    float* W1s = (float*)(ws + 0);                        //  4,737,024 B (2313 rows x 2 halves)
    uint32_t* bits1 = (uint32_t*)(ws + 4737024);          //  3,270,400 B
    float* z1ct = (float*)(ws + 8007424);                 // 22,937,600 B
    // z2ct aliases bits1's region: bits1 is dead after k3, z2ct written by k45.
    float* z2ct = (float*)(ws + 4737024);                 //    448,000 B (alias)
    // total: 30,945,024 B

    k12<<<NW32 * B_SZ + NW32 * 16 + 1, 384, 0, stream>>>(spikeInput, W1, bits1, W1s);
    k3_dense1<<<dim3(NGRP, 2), 256, 0, stream>>>(bits1, W1s, z1ct);
    k45<<<B_SZ * NCHUNK, 512, 0, stream>>>(z1ct, W2, z2ct);
    k6_fir_scan2<<<5 * NCHUNK, 64, 0, stream>>>(z2ct, out);
}

// Round 13
// 315.011 us; speedup vs baseline: 2.2057x; 2.2057x over previous
//
#include <hip/hip_runtime.h>
#include <stdint.h>

// Problem constants
#define B_SZ   32
#define NIN    2312
#define NHID   512
#define NOUT   10
#define T_SZ   350
#define NW32   73                 // ceil(2312/32) bitmask words per input column
#define NW64   8                  // 512/64 ballot words per hidden column
#define NHALF  256                // output half-width for L2-resident W1
#define NROW   2313               // NIN + 1 dummy zero row (branch-free padding)

// psp (SRM) kernel eps[n] = CS * n * DS^n, DS = exp(-0.1), CS = e/10
#define DS_D   0.9048374180359595
#define CS_D   0.2718281828459045
#define D100_D 4.5399929762484854e-05   // exp(-10) = DS^100
// refractory recurrence in fp32, exactly like the reference scan
#define DREF_F 0.36787944117144233f     // exp(-1)
#define CREF_F -54.36563656918091f      // -2*10*e

// scan chunking (k45/k6): 7 chunks of 50; psp-IIR warm-started <=100 steps
// early is EXACT (FIR truncated at 100 taps); refractory burn-in error decays
// e^-n -> < 1e-28 by chunk start (absorbed below fp32 ulp).
#define NCHUNK 7
#define CLEN   50
#define NPF    10                 // ring depth; 50/100/150 all %10==0

// ---------------------------------------------------------------------------
// K12: fused bitpack (blocks 0..2335) + W1 half-split pack (2336..3503) +
//      dummy-zero-row fill (block 3504). Bitpack float4 streaming.
__global__ __launch_bounds__(384) void k12(const float* __restrict__ x,
                                           const float* __restrict__ W1,
                                           uint32_t* __restrict__ bits1,
                                           float* __restrict__ W1s) {
    __shared__ float lds[32 * T_SZ];   // 44.8 KB
    const int bid = blockIdx.x;
    const int tid = threadIdx.x;
    if (bid < NW32 * B_SZ) {
        // --- bitpack: block = (b, w); contiguous rowsx350 tile -> LDS -> pack
        const int w = bid % NW32;
        const int b = bid / NW32;
        const int rows = (NIN - (w << 5) < 32) ? (NIN - (w << 5)) : 32;  // 32 or 8
        const float* base = x + ((size_t)(b * NIN + (w << 5))) * T_SZ;
        const int nf4 = (rows * T_SZ) >> 2;     // rows even -> divisible by 4
        for (int f = tid; f < nf4; f += 384)
            ((float4*)lds)[f] = ((const float4*)base)[f];
        __syncthreads();
        if (tid < T_SZ) {
            uint32_t bits = 0;
            for (int j = 0; j < rows; ++j)
                bits |= (lds[j * T_SZ + tid] > 0.5f) ? (1u << j) : 0u;
            bits1[(size_t)(b * T_SZ + tid) * NW32 + w] = bits;
        }
    } else if (bid < NW32 * B_SZ + NW32 * 16) {
        // --- pack W1 [512, 2312] -> W1s[h][i][256], h = o>>8
        float (*tile)[33] = (float (*)[33])lds;
        const int bb = bid - NW32 * B_SZ;
        const int i0 = (bb % NW32) * 32, o0 = (bb / NW32) * 32;
        const int tx = tid & 31, ty = tid >> 5;  // ty 0..11
#pragma unroll
        for (int r = 0; r < 3; ++r) {
            int row = ty + 12 * r;
            if (row < 32) {
                int o = o0 + row, i = i0 + tx;
                if (i < NIN) tile[row][tx] = W1[(size_t)o * NIN + i];
            }
        }
        __syncthreads();
#pragma unroll
        for (int r = 0; r < 3; ++r) {
            int row = ty + 12 * r;
            if (row < 32) {
                int i = i0 + row, o = o0 + tx;
                if (i < NIN)
                    W1s[((size_t)(o >> 8) * NROW + i) * NHALF + (o & 255)] = tile[tx][row];
            }
        }
    } else {
        // --- dummy zero row i = NIN for both halves
        if (tid < NHALF) {
            W1s[((size_t)0 * NROW + NIN) * NHALF + tid] = 0.0f;
            W1s[((size_t)1 * NROW + NIN) * NHALF + tid] = 0.0f;
        }
    }
}

// ---------------------------------------------------------------------------
// K3: sparse dense1 (R6/R10 gather form — the measured optimum: 101us,
// 26.3 TB/s L2-gather = 76% of streaming ubench). Half-split for L2
// residency; single-wave shfl prefix scan; branch-free 4-deep pipelined row
// loop via dummy zero-row padding. Batching/LDS-staging variants all lose
// (R7/R8/R9/R11/R12 post-mortems): VALU/divergence tax > traffic savings.
__global__ __launch_bounds__(256) void k3_dense1(const uint32_t* __restrict__ bits1,
                                                 const float* __restrict__ W1s,
                                                 float* __restrict__ z1ct) {
    __shared__ uint32_t words[128];
    __shared__ uint16_t pfx[80];
    __shared__ uint16_t idxbuf[NIN + 16];
    __shared__ float red[3][NHALF];
    __shared__ float fin[NHALF];

    const int bt = blockIdx.x;          // b*350 + t
    const int h = blockIdx.y;           // 0 or 1
    const int tid = threadIdx.x;
    const int wv = tid >> 6, lane = tid & 63;

    if (tid < 128) words[tid] = (tid < NW32) ? bits1[(size_t)bt * NW32 + tid] : 0u;
    __syncthreads();

    if (wv == 0) {
        uint32_t w0 = words[lane];
        uint32_t w1 = words[lane + 64];
        int p0 = __popc(w0), p1 = __popc(w1);
        int s0 = p0, s1 = p1;
#pragma unroll
        for (int off = 1; off < 64; off <<= 1) {
            int u0 = __shfl_up(s0, off);
            int u1 = __shfl_up(s1, off);
            if (lane >= off) { s0 += u0; s1 += u1; }
        }
        int tot0 = __shfl(s0, 63);
        pfx[lane] = (uint16_t)(s0 - p0);
        if (lane < 9) pfx[lane + 64] = (uint16_t)(tot0 + s1 - p1);
        if (lane == 8) pfx[73] = (uint16_t)(tot0 + s1);   // ntot
    }
    __syncthreads();

    const int ntot = pfx[73];
    const int npad = (ntot + 15) & ~15;
    if (tid < NW32) {
        uint32_t m = words[tid];
        int p = pfx[tid];
        while (m) {
            int j = __builtin_ctz(m);
            m &= m - 1;
            idxbuf[p++] = (uint16_t)((tid << 5) + j);
        }
    }
    if (tid >= 240) {                   // pad to multiple of 16 with zero row
        int k = tid - 240;
        if (ntot + k < npad) idxbuf[ntot + k] = (uint16_t)NIN;
    }
    __syncthreads();

    const float* Wh = W1s + (size_t)h * NROW * NHALF;
    float4 acc = make_float4(0.f, 0.f, 0.f, 0.f);
    for (int r = wv; r < npad; r += 16) {
        int i0 = idxbuf[r], i1 = idxbuf[r + 4], i2 = idxbuf[r + 8], i3 = idxbuf[r + 12];
        float4 v0 = ((const float4*)(Wh + (size_t)i0 * NHALF))[lane];
        float4 v1 = ((const float4*)(Wh + (size_t)i1 * NHALF))[lane];
        float4 v2 = ((const float4*)(Wh + (size_t)i2 * NHALF))[lane];
        float4 v3 = ((const float4*)(Wh + (size_t)i3 * NHALF))[lane];
        acc.x += v0.x; acc.y += v0.y; acc.z += v0.z; acc.w += v0.w;
        acc.x += v1.x; acc.y += v1.y; acc.z += v1.z; acc.w += v1.w;
        acc.x += v2.x; acc.y += v2.y; acc.z += v2.z; acc.w += v2.w;
        acc.x += v3.x; acc.y += v3.y; acc.z += v3.z; acc.w += v3.w;
    }
    if (wv > 0) ((float4*)red[wv - 1])[lane] = acc;
    __syncthreads();
    if (wv == 0) {
        float4 a1 = ((float4*)red[0])[lane];
        float4 a2 = ((float4*)red[1])[lane];
        float4 a3 = ((float4*)red[2])[lane];
        acc.x = ((acc.x + a1.x) + a2.x) + a3.x;
        acc.y = ((acc.y + a1.y) + a2.y) + a3.y;
        acc.z = ((acc.z + a1.z) + a2.z) + a3.z;
        acc.w = ((acc.w + a1.w) + a2.w) + a3.w;
        ((float4*)fin)[lane] = acc;
    }
    __syncthreads();
    const int och = (h << 8) + tid;
    const int oc = och >> 6, l6 = och & 63;
    const int b = bt / T_SZ, t = bt - b * T_SZ;
    z1ct[((size_t)(b * NW64 + oc) * T_SZ + t) * 64 + l6] = fin[tid];
}

// ---------------------------------------------------------------------------
// K45: fused layer-1 scan + dense2. Block = (b, chunk), 512 threads = 8 waves;
// wave wv scans channels wv*64..+63 (chunked IIR, exact), ballots into LDS;
// then 500 (t,o) pairs compute z2 in the same wv/ctz-ascending order.
__global__ __launch_bounds__(512) void k45(const float* __restrict__ z1ct,
                                           const float* __restrict__ W2,
                                           float* __restrict__ z2ct) {
    __shared__ float W2s[NHID * NOUT];      // [c][o], 20 KB
    __shared__ uint64_t sw[CLEN][NW64];     // s1 ballot words for my 50 t's
    const int tid = threadIdx.x;
    const int wv = tid >> 6, lane = tid & 63;
    const int b = blockIdx.x / NCHUNK;
    const int ck = blockIdx.x % NCHUNK;
    const int tstart = ck * CLEN;
    const int tend = tstart + CLEN;
    const int t0 = (tstart >= 100) ? tstart - 100 : 0;

    for (int k = tid; k < NHID * NOUT; k += 512) {
        int c = k / NOUT, o = k - c * NOUT;
        W2s[k] = W2[(size_t)o * NHID + c];
    }

    // ---- layer-1 chunked scan (identical math to old k4)
    const float* base = z1ct + (size_t)(b * NW64 + wv) * T_SZ * 64 + lane;
    double A = 0.0, Bs = 0.0, A2 = 0.0, Bs2 = 0.0;
    float ra = 0.0f, rb = 0.0f;
    const double TAIL = D100_D * CS_D;
    float xb[NPF], xdb[NPF];
#pragma unroll
    for (int i = 0; i < NPF; ++i) {
        int t = t0 + i;
        xb[i] = base[(size_t)t * 64];
        int td = t - 100;
        xdb[i] = (td >= 0) ? base[(size_t)td * 64] : 0.0f;
    }
    for (int tb = t0; tb < tend; tb += NPF) {
#pragma unroll
        for (int i = 0; i < NPF; ++i) {
            const int t = tb + i;
            float x = xb[i], xd = xdb[i];
            const int tn = t + NPF;
            xb[i] = (tn < T_SZ) ? base[(size_t)tn * 64] : 0.0f;
            const int td = tn - 100;
            xdb[i] = (td >= 0) ? base[(size_t)td * 64] : 0.0f;
            Bs = DS_D * Bs + DS_D * A;
            A = DS_D * A + (double)x;
            Bs2 = DS_D * Bs2 + DS_D * A2;
            A2 = DS_D * A2 + (double)xd;
            double y = CS_D * Bs - TAIL * (Bs2 + 100.0 * A2);
            float u = (float)y + CREF_F * rb;
            float s = (u >= 10.0f) ? 1.0f : 0.0f;
            float ran = DREF_F * ra + s;
            float rbn = DREF_F * rb + DREF_F * ra;
            ra = ran; rb = rbn;
            uint64_t mball = __ballot(s != 0.0f);
            if (t >= tstart && lane == 0) sw[t - tstart][wv] = mball;
        }
    }
    __syncthreads();

    // ---- dense2 for my 50 t's (same order as old k5 -> bit-identical)
    if (tid < CLEN * NOUT) {                // 500 of 512
        const int tr = tid / NOUT;
        const int o = tid - tr * NOUT;
        const int t = tstart + tr;
        float acc = 0.f;
#pragma unroll
        for (int w2 = 0; w2 < NW64; ++w2) {
            uint64_t m = sw[tr][w2];
            while (m) {
                int j = __builtin_ctzll(m);
                m &= m - 1;
                acc += W2s[((w2 << 6) + j) * NOUT + o];
            }
        }
        const int bo = b * NOUT + o;
        z2ct[((size_t)(bo >> 6) * T_SZ + t) * 64 + (bo & 63)] = acc;
    }
}

// ---------------------------------------------------------------------------
// K6: fused psp-IIR + refractory scan, layer 2, chunked. Writes [B, NOUT, T].
__global__ __launch_bounds__(64) void k6_fir_scan2(const float* __restrict__ z2ct,
                                                   float* __restrict__ out) {
    const int lane = threadIdx.x;
    const int g = blockIdx.x / NCHUNK;    // bo group 0..4
    const int ck = blockIdx.x % NCHUNK;
    const int tstart = ck * CLEN;
    const int tend = tstart + CLEN;
    const int t0 = (tstart >= 100) ? tstart - 100 : 0;
    const int bo = (g << 6) + lane;       // 0..319
    const float* base = z2ct + (size_t)g * T_SZ * 64 + lane;
    float* op = out + (size_t)bo * T_SZ;
    double A = 0.0, Bs = 0.0, A2 = 0.0, Bs2 = 0.0;
    float ra = 0.0f, rb = 0.0f;
    const double TAIL = D100_D * CS_D;
    float xb[NPF], xdb[NPF];
#pragma unroll
    for (int i = 0; i < NPF; ++i) {
        int t = t0 + i;
        xb[i] = base[(size_t)t * 64];
        int td = t - 100;
        xdb[i] = (td >= 0) ? base[(size_t)td * 64] : 0.0f;
    }
    for (int tb = t0; tb < tend; tb += NPF) {
#pragma unroll
        for (int i = 0; i < NPF; ++i) {
            const int t = tb + i;
            float x = xb[i], xd = xdb[i];
            const int tn = t + NPF;
            xb[i] = (tn < T_SZ) ? base[(size_t)tn * 64] : 0.0f;
            const int td = tn - 100;
            xdb[i] = (td >= 0) ? base[(size_t)td * 64] : 0.0f;
            Bs = DS_D * Bs + DS_D * A;
            A = DS_D * A + (double)x;
            Bs2 = DS_D * Bs2 + DS_D * A2;
            A2 = DS_D * A2 + (double)xd;
            double y = CS_D * Bs - TAIL * (Bs2 + 100.0 * A2);
            float u = (float)y + CREF_F * rb;
            float s = (u >= 10.0f) ? 1.0f : 0.0f;
            float ran = DREF_F * ra + s;
            float rbn = DREF_F * rb + DREF_F * ra;
            ra = ran; rb = rbn;
            if (t >= tstart) op[t] = s;
        }
    }
}

// ---------------------------------------------------------------------------
extern "C" void kernel_launch(void* const* d_in, const int* in_sizes, int n_in,
                              void* d_out, int out_size, void* d_ws, size_t ws_size,
                              hipStream_t stream) {
    const float* spikeInput = (const float*)d_in[0];  // [32, 2312, 350]
    const float* W1 = (const float*)d_in[1];          // [512, 2312]
    const float* W2 = (const float*)d_in[2];          // [10, 512]
    float* out = (float*)d_out;                       // [32, 10, 350]

    char* ws = (char*)d_ws;
    float* W1s = (float*)(ws + 0);                        //  4,737,024 B (2313 rows x 2 halves)
    uint32_t* bits1 = (uint32_t*)(ws + 4737024);          //  3,270,400 B
    float* z1ct = (float*)(ws + 8007424);                 // 22,937,600 B
    // z2ct aliases bits1's region: bits1 is dead after k3, z2ct written by k45.
    float* z2ct = (float*)(ws + 4737024);                 //    448,000 B (alias)
    // total: 30,945,024 B

    k12<<<NW32 * B_SZ + NW32 * 16 + 1, 384, 0, stream>>>(spikeInput, W1, bits1, W1s);
    k3_dense1<<<dim3(B_SZ * T_SZ, 2), 256, 0, stream>>>(bits1, W1s, z1ct);
    k45<<<B_SZ * NCHUNK, 512, 0, stream>>>(z1ct, W2, z2ct);
    k6_fir_scan2<<<5 * NCHUNK, 64, 0, stream>>>(z2ct, out);
}